// Round 3
// baseline (1475.900 us; speedup 1.0000x reference)
//
#include <hip/hip_runtime.h>
#include <cstdint>
#include <cstddef>

// SAGE 3-layer GNN, MI355X gfx950 — round 6:
//  * aggregate: column-slice XCD affinity. Work unit = (node, 64B-slice);
//    slice id == blockIdx.x & 7 -> lands on a fixed XCD (bid%8 round-robin),
//    so each XCD's private L2 only caches 1/8 of the feature matrix
//    (6.4MB vs 51.2MB). col_idx loaded nontemporally so the 8x re-read
//    stream doesn't evict the hot slice. (Round-5 post-mortem: aggregate is
//    L2-miss-bandwidth-bound at ~6.3 TB/s fabric; MLP depth did nothing.)
//  * GEMM / CSR / prep unchanged from round 5.

#define N_NODES 100000
#define N_EDGES 1600000

#define SCAN_BLOCKS 256
#define SCAN_T 256
#define FILL_PASSES 4

// aggregate grid: 8 slices x AGG_CHUNKS chunks, 4 waves/block
#define AGG_CHUNKS 2048

typedef unsigned short ushort;
typedef unsigned int uint;
typedef __attribute__((ext_vector_type(8))) short short8;
typedef __attribute__((ext_vector_type(4))) float floatx4;

#define AS1 __attribute__((address_space(1)))
#define AS3 __attribute__((address_space(3)))

__device__ __forceinline__ float bf2f(ushort h) {
    union { uint u; float f; } c; c.u = ((uint)h) << 16; return c.f;
}
__device__ __forceinline__ ushort f2bf(float f) {
    union { float f; uint u; } c; c.f = f;
    uint u = c.u;
    return (ushort)((u + 0x7FFFu + ((u >> 16) & 1u)) >> 16);  // RTNE
}

// ---------------- fused prep: count_edges + convert_x + 6 W transposes ----

#define N4X (N_NODES * 128 / 4)

__global__ void prep_all(
    const int* __restrict__ dst, int* __restrict__ cnt,
    const float* __restrict__ x, ushort* __restrict__ xb,
    const float* __restrict__ Wl0, ushort* __restrict__ Wl0t,
    const float* __restrict__ Wr0, ushort* __restrict__ Wr0t,
    const float* __restrict__ Wl1, ushort* __restrict__ Wl1t,
    const float* __restrict__ Wr1, ushort* __restrict__ Wr1t,
    const float* __restrict__ Wl2, ushort* __restrict__ Wl2t,
    const float* __restrict__ Wr2, ushort* __restrict__ Wr2t)
{
    int i = blockIdx.x * blockDim.x + threadIdx.x;
    if (i < N_EDGES) { atomicAdd(&cnt[dst[i]], 1); return; }
    i -= N_EDGES;
    if (i < N4X) {
        float4 v = *(const float4*)&x[(size_t)i * 4];
        ushort4 o;
        o.x = f2bf(v.x); o.y = f2bf(v.y); o.z = f2bf(v.z); o.w = f2bf(v.w);
        *(ushort4*)&xb[(size_t)i * 4] = o;
        return;
    }
    i -= N4X;
    // transposes: Wt[n*K + k] = W[k*256 + n]
    if (i < 32768) { Wl0t[i] = f2bf(Wl0[(i & 127) * 256 + (i >> 7)]); return; }
    i -= 32768;
    if (i < 32768) { Wr0t[i] = f2bf(Wr0[(i & 127) * 256 + (i >> 7)]); return; }
    i -= 32768;
    if (i < 65536) { Wl1t[i] = f2bf(Wl1[(i & 255) * 256 + (i >> 8)]); return; }
    i -= 65536;
    if (i < 65536) { Wr1t[i] = f2bf(Wr1[(i & 255) * 256 + (i >> 8)]); return; }
    i -= 65536;
    if (i < 65536) { Wl2t[i] = f2bf(Wl2[(i & 255) * 256 + (i >> 8)]); return; }
    i -= 65536;
    if (i < 65536) { Wr2t[i] = f2bf(Wr2[(i & 255) * 256 + (i >> 8)]); return; }
}

// ---------------- CSR scan ----------------

__global__ __launch_bounds__(SCAN_T) void scan_partial(
    const int* __restrict__ cnt, int* __restrict__ bsum, int n)
{
    int chunk = (n + SCAN_BLOCKS - 1) / SCAN_BLOCKS;
    int beg = blockIdx.x * chunk;
    int end = beg + chunk; if (end > n) end = n;
    int t = threadIdx.x;
    int s = 0;
    for (int i = beg + t; i < end; i += SCAN_T) s += cnt[i];
    __shared__ int sh[SCAN_T];
    sh[t] = s;
    __syncthreads();
    for (int off = SCAN_T / 2; off > 0; off >>= 1) {
        if (t < off) sh[t] += sh[t + off];
        __syncthreads();
    }
    if (t == 0) bsum[blockIdx.x] = sh[0];
}

__global__ __launch_bounds__(SCAN_T) void scan_block_sums(int* __restrict__ bsum) {
    int t = threadIdx.x;
    __shared__ int sh[SCAN_T];
    int v = bsum[t];
    sh[t] = v;
    __syncthreads();
    for (int off = 1; off < SCAN_T; off <<= 1) {
        int u = (t >= off) ? sh[t - off] : 0;
        __syncthreads();
        sh[t] += u;
        __syncthreads();
    }
    bsum[t] = sh[t] - v;  // exclusive
}

__global__ __launch_bounds__(SCAN_T) void scan_fill(
    int* __restrict__ cnt, const int* __restrict__ bsum,
    int* __restrict__ row_ptr, int n)
{
    int chunk = (n + SCAN_BLOCKS - 1) / SCAN_BLOCKS;
    int beg = blockIdx.x * chunk;
    int end = beg + chunk; if (end > n) end = n;
    int t = threadIdx.x;
    int per = (chunk + SCAN_T - 1) / SCAN_T;
    int tb = beg + t * per;
    int te = tb + per; if (te > end) te = end;
    int s = 0;
    for (int i = tb; i < te; ++i) s += cnt[i];
    __shared__ int sh[SCAN_T];
    sh[t] = s;
    __syncthreads();
    for (int off = 1; off < SCAN_T; off <<= 1) {
        int u = (t >= off) ? sh[t - off] : 0;
        __syncthreads();
        sh[t] += u;
        __syncthreads();
    }
    int running = bsum[blockIdx.x] + sh[t] - s;
    for (int i = tb; i < te; ++i) {
        int c = cnt[i];
        row_ptr[i] = running;
        cnt[i] = running;  // becomes fill cursor
        running += c;
    }
    if (blockIdx.x == 0 && t == 0) row_ptr[n] = N_EDGES;
}

// 4 dst-range passes: per-pass dirty col_idx region (~1.6MB) stays L2-resident.
__global__ void fill_csr(const int* __restrict__ src, const int* __restrict__ dst,
                         int* __restrict__ cursor, int* __restrict__ col_idx) {
    int i = blockIdx.x * blockDim.x + threadIdx.x;
    if (i >= N_EDGES) return;
    int lo = (int)blockIdx.y * (N_NODES / FILL_PASSES);
    int hi = lo + (N_NODES / FILL_PASSES);
    int d = dst[i];
    if (d >= lo && d < hi) {
        int p = atomicAdd(&cursor[d], 1);
        col_idx[p] = src[i];
    }
}

// ---------------- mean aggregation: column-slice XCD affinity ----------------
// Work unit = (node, slice). slice covers 64B (32 bf16) of the row.
// F=256: 8 slices; F=128: 4 slices. blockIdx.x & 7 selects the slice group,
// so on the (empirical) bid%8 XCD round-robin every XCD only touches its own
// 64B columns of xb -> per-XCD L2 working set 6.4MB instead of 51.2MB.
// Per edge: 16 lanes x 4B; 4 edges per load instruction; fp32 accum;
// combine the 4 lane-groups with 2 shfl_xor. col_idx read nontemporally.
__global__ __launch_bounds__(256) void aggregate_slice(
    const ushort* __restrict__ xb, const int* __restrict__ row_ptr,
    const int* __restrict__ col_idx, ushort* __restrict__ outb, int F)
{
    int lane = threadIdx.x & 63;
    int w = threadIdx.x >> 6;
    int q = lane >> 4;       // edge sub-slot 0..3
    int j = lane & 15;       // column pair within slice
    int nslice = (F == 256) ? 8 : 4;
    int slice = blockIdx.x & (nslice - 1);
    int chunk = blockIdx.x >> 3;          // 0 .. AGG_CHUNKS-1 (F=256)
    if (F == 128) chunk = blockIdx.x >> 2;
    int c = slice * 32 + j * 2;           // ushort offset within row
    int node0 = chunk * 4 + w;
    int nstride = AGG_CHUNKS * 4;

    for (int node = node0; node < N_NODES; node += nstride) {
        int b = row_ptr[node], e = row_ptr[node + 1];
        float d = (float)(e - b); if (d < 1.f) d = 1.f;
        float inv = 1.f / d;
        float a0 = 0.f, a1 = 0.f;
        int i = b;
        for (; i + 15 < e; i += 16) {
            int s0 = __builtin_nontemporal_load(&col_idx[i + q]);
            int s1 = __builtin_nontemporal_load(&col_idx[i + 4 + q]);
            int s2 = __builtin_nontemporal_load(&col_idx[i + 8 + q]);
            int s3 = __builtin_nontemporal_load(&col_idx[i + 12 + q]);
            uint v0 = *(const uint*)&xb[(size_t)s0 * F + c];
            uint v1 = *(const uint*)&xb[(size_t)s1 * F + c];
            uint v2 = *(const uint*)&xb[(size_t)s2 * F + c];
            uint v3 = *(const uint*)&xb[(size_t)s3 * F + c];
            a0 += bf2f((ushort)(v0 & 0xffff)); a1 += bf2f((ushort)(v0 >> 16));
            a0 += bf2f((ushort)(v1 & 0xffff)); a1 += bf2f((ushort)(v1 >> 16));
            a0 += bf2f((ushort)(v2 & 0xffff)); a1 += bf2f((ushort)(v2 >> 16));
            a0 += bf2f((ushort)(v3 & 0xffff)); a1 += bf2f((ushort)(v3 >> 16));
        }
        for (; i + 3 < e; i += 4) {
            int s0 = __builtin_nontemporal_load(&col_idx[i + q]);
            uint v0 = *(const uint*)&xb[(size_t)s0 * F + c];
            a0 += bf2f((ushort)(v0 & 0xffff)); a1 += bf2f((ushort)(v0 >> 16));
        }
        int rem = e - i;
        if (q < rem) {
            int s0 = __builtin_nontemporal_load(&col_idx[i + q]);
            uint v0 = *(const uint*)&xb[(size_t)s0 * F + c];
            a0 += bf2f((ushort)(v0 & 0xffff)); a1 += bf2f((ushort)(v0 >> 16));
        }
        a0 += __shfl_xor(a0, 16); a0 += __shfl_xor(a0, 32);
        a1 += __shfl_xor(a1, 16); a1 += __shfl_xor(a1, 32);
        if (q == 0) {
            ushort2 o;
            o.x = f2bf(a0 * inv);
            o.y = f2bf(a1 * inv);
            *(ushort2*)&outb[(size_t)node * F + c] = o;  // 16 lanes x 4B = 64B line
        }
    }
}

// ---------------- W-resident dual MFMA GEMM, full 256-col tile ----------------
// C[M,256] = relu?( A1[M,K]@W1 + A2[M,K]@W2 + bias ).
// 512 thr (8 waves), tile 256 rows x 256 cols. W-half for one mm phase lives
// in 128KB LDS (loaded once per phase); A-frags straight global->VGPR
// (16 rows x 64B per wave, coalesced). K-loop: no barriers, no vmcnt drains.
__global__ __launch_bounds__(512, 1) void gemm_wres(
    const ushort* __restrict__ A1, const ushort* __restrict__ W1t,
    const ushort* __restrict__ A2, const ushort* __restrict__ W2t,
    const float* __restrict__ bias, ushort* __restrict__ out_bf,
    float* __restrict__ out_f32, int M, int K, int relu)
{
    __shared__ __align__(16) ushort Wl[32 * 256 * 8];  // 128KB, K<=256
    int tid = threadIdx.x;
    int w = tid >> 6, lane = tid & 63;
    int m_ = lane & 15, koq = lane >> 4;
    int row0 = blockIdx.x * 256;
    int KQ = K >> 3;               // 16B k-chunks per W column
    int nj = (KQ * 256) >> 9;      // staging rounds (slots/512)
    int nk = K >> 5;               // MFMA K-steps per mm

    floatx4 acc[2][16];
#pragma unroll
    for (int i = 0; i < 2; ++i)
#pragma unroll
        for (int f = 0; f < 16; ++f) acc[i][f] = (floatx4){0.f, 0.f, 0.f, 0.f};

    int ra = row0 + w * 32 + m_;      if (ra > M - 1) ra = M - 1;
    int rb = row0 + w * 32 + 16 + m_; if (rb > M - 1) rb = M - 1;

    for (int mm = 0; mm < 2; ++mm) {
        const ushort* __restrict__ A  = mm ? A2 : A1;
        const ushort* __restrict__ Wt = mm ? W2t : W1t;
        if (mm) __syncthreads();  // all waves done reading Wl before overwrite
        for (int j = 0; j < nj; ++j) {
            int s = j * 512 + tid;
            int q = s >> 8, col = s & 255;
            __builtin_amdgcn_global_load_lds(
                (const AS1 uint*)&Wt[(size_t)col * K + q * 8],
                (AS3 uint*)&Wl[(size_t)(j * 512 + w * 64) * 8], 16, 0, 0);
        }
        __syncthreads();

        const ushort* __restrict__ Aa = &A[(size_t)ra * K + koq * 8];
        const ushort* __restrict__ Ab = &A[(size_t)rb * K + koq * 8];

        short8 a0 = *(const short8*)&Aa[0];
        short8 a1 = *(const short8*)&Ab[0];
        for (int kk = 0; kk < nk; ++kk) {
            short8 n0, n1;
            if (kk + 1 < nk) {            // prefetch next A-frags
                n0 = *(const short8*)&Aa[(kk + 1) * 32];
                n1 = *(const short8*)&Ab[(kk + 1) * 32];
            }
            const ushort* bbase = &Wl[(size_t)((kk * 4 + koq) * 256 + m_) * 8];
#pragma unroll
            for (int fc = 0; fc < 16; ++fc) {
                short8 b = *(const short8*)&bbase[fc * 128];
                acc[0][fc] = __builtin_amdgcn_mfma_f32_16x16x32_bf16(a0, b, acc[0][fc], 0, 0, 0);
                acc[1][fc] = __builtin_amdgcn_mfma_f32_16x16x32_bf16(a1, b, acc[1][fc], 0, 0, 0);
            }
            a0 = n0; a1 = n1;
        }
    }

    // epilogue: frag C layout col = m_, row = koq*4 + r
#pragma unroll
    for (int m2 = 0; m2 < 2; ++m2) {
#pragma unroll
        for (int fc = 0; fc < 16; ++fc) {
            int col = fc * 16 + m_;
            float bv = bias[col];
#pragma unroll
            for (int r = 0; r < 4; ++r) {
                int row = row0 + w * 32 + m2 * 16 + koq * 4 + r;
                if (row >= M) continue;
                float v = acc[m2][fc][r] + bv;
                if (relu) v = fmaxf(v, 0.f);
                if (out_f32) out_f32[(size_t)row * 256 + col] = v;
                else         out_bf [(size_t)row * 256 + col] = f2bf(v);
            }
        }
    }
}

// ---------------- launch ----------------

extern "C" void kernel_launch(void* const* d_in, const int* in_sizes, int n_in,
                              void* d_out, int out_size, void* d_ws, size_t ws_size,
                              hipStream_t stream) {
    const float* x    = (const float*)d_in[0];
    const float* W_l0 = (const float*)d_in[1];
    const float* b_l0 = (const float*)d_in[2];
    const float* W_r0 = (const float*)d_in[3];
    const float* W_l1 = (const float*)d_in[4];
    const float* b_l1 = (const float*)d_in[5];
    const float* W_r1 = (const float*)d_in[6];
    const float* W_l2 = (const float*)d_in[7];
    const float* b_l2 = (const float*)d_in[8];
    const float* W_r2 = (const float*)d_in[9];
    const int* esrc   = (const int*)d_in[10];
    const int* edst   = (const int*)d_in[11];
    float* out = (float*)d_out;

    size_t off = 0;
    char* ws = (char*)d_ws;
    auto take = [&](size_t bytes) -> void* {
        void* p = ws + off;
        off += (bytes + 255) & ~(size_t)255;
        return p;
    };
    int*    cnt     = (int*)take((size_t)N_NODES * 4);
    int*    row_ptr = (int*)take((size_t)(N_NODES + 1) * 4);
    int*    col_idx = (int*)take((size_t)N_EDGES * 4);
    int*    bsum    = (int*)take((size_t)SCAN_BLOCKS * 4);
    ushort* xb      = (ushort*)take((size_t)N_NODES * 128 * 2);
    ushort* Wl0t    = (ushort*)take((size_t)256 * 128 * 2);
    ushort* Wr0t    = (ushort*)take((size_t)256 * 128 * 2);
    ushort* Wl1t    = (ushort*)take((size_t)256 * 256 * 2);
    ushort* Wr1t    = (ushort*)take((size_t)256 * 256 * 2);
    ushort* Wl2t    = (ushort*)take((size_t)256 * 256 * 2);
    ushort* Wr2t    = (ushort*)take((size_t)256 * 256 * 2);
    ushort* aggrb   = (ushort*)take((size_t)N_NODES * 256 * 2);
    ushort* ha      = (ushort*)take((size_t)N_NODES * 256 * 2);
    ushort* hb      = (ushort*)take((size_t)N_NODES * 256 * 2);
    (void)ws_size; (void)in_sizes; (void)n_in; (void)out_size;

    // prep: zero cnt, then fused count+convert+transposes
    hipMemsetAsync(cnt, 0, (size_t)N_NODES * 4, stream);
    int total_prep = N_EDGES + N4X + 2 * 32768 + 4 * 65536;
    prep_all<<<(total_prep + 255) / 256, 256, 0, stream>>>(
        edst, cnt, x, xb,
        W_l0, Wl0t, W_r0, Wr0t, W_l1, Wl1t, W_r1, Wr1t, W_l2, Wl2t, W_r2, Wr2t);

    // CSR scan + fill
    scan_partial<<<SCAN_BLOCKS, SCAN_T, 0, stream>>>(cnt, bsum, N_NODES);
    scan_block_sums<<<1, SCAN_T, 0, stream>>>(bsum);
    scan_fill<<<SCAN_BLOCKS, SCAN_T, 0, stream>>>(cnt, bsum, row_ptr, N_NODES);
    int eb = (N_EDGES + 255) / 256;
    fill_csr<<<dim3(eb, FILL_PASSES), 256, 0, stream>>>(esrc, edst, cnt, col_idx);

    dim3 ggrid((N_NODES + 255) / 256, 1);

    // layer 0: 128 -> 256, relu   (4 slices x AGG_CHUNKS blocks)
    aggregate_slice<<<AGG_CHUNKS * 4, 256, 0, stream>>>(xb, row_ptr, col_idx, aggrb, 128);
    gemm_wres<<<ggrid, 512, 0, stream>>>(aggrb, Wl0t, xb, Wr0t, b_l0,
                                         ha, nullptr, N_NODES, 128, 1);
    // layer 1: 256 -> 256, relu   (8 slices x AGG_CHUNKS blocks)
    aggregate_slice<<<AGG_CHUNKS * 8, 256, 0, stream>>>(ha, row_ptr, col_idx, aggrb, 256);
    gemm_wres<<<ggrid, 512, 0, stream>>>(aggrb, Wl1t, ha, Wr1t, b_l1,
                                         hb, nullptr, N_NODES, 256, 1);
    // layer 2: 256 -> 256, no relu, fp32 out
    aggregate_slice<<<AGG_CHUNKS * 8, 256, 0, stream>>>(hb, row_ptr, col_idx, aggrb, 256);
    gemm_wres<<<ggrid, 512, 0, stream>>>(aggrb, Wl2t, hb, Wr2t, b_l2,
                                         nullptr, out, N_NODES, 256, 0);
}

// Round 4
// 808.938 us; speedup vs baseline: 1.8245x; 1.8245x over previous
//
#include <hip/hip_runtime.h>
#include <cstdint>
#include <cstddef>

// SAGE 3-layer GNN, MI355X gfx950 — round 7:
//  * aggregate: REVERTED to round-4 form (1 wave/node, 2-edge unroll) —
//    measured best (114 µs) and at compulsory-miss floor (FETCH 386 MB ≈
//    353 MB per-XCD compulsory). Round-6 slice experiment refuted affinity.
//  * GEMM: new gemm_kc — 128x256 tile, A read ONCE, W double-buffered in
//    2x32KB LDS K-chunks (stage overlaps compute), W pre-transposed into
//    LDS slot order so staging is lane-coalesced. 2 blocks/CU.
//  * prep_all fusion + 4-pass fill_csr kept.

#define N_NODES 100000
#define N_EDGES 1600000

#define SCAN_BLOCKS 256
#define SCAN_T 256
#define FILL_PASSES 4

typedef unsigned short ushort;
typedef unsigned int uint;
typedef __attribute__((ext_vector_type(8))) short short8;
typedef __attribute__((ext_vector_type(4))) float floatx4;

#define AS1 __attribute__((address_space(1)))
#define AS3 __attribute__((address_space(3)))

__device__ __forceinline__ float bf2f(ushort h) {
    union { uint u; float f; } c; c.u = ((uint)h) << 16; return c.f;
}
__device__ __forceinline__ ushort f2bf(float f) {
    union { float f; uint u; } c; c.f = f;
    uint u = c.u;
    return (ushort)((u + 0x7FFFu + ((u >> 16) & 1u)) >> 16);  // RTNE
}

// ---------------- fused prep: count_edges + convert_x + 6 W transposes ----
// W [K,256] f32  ->  Wt2 in LDS-slot order: elem i = ((q*256 + col)*8 + e),
// where k = q*8 + e. Staging then reads 16B/lane fully coalesced.

#define N4X (N_NODES * 128 / 4)

__global__ void prep_all(
    const int* __restrict__ dst, int* __restrict__ cnt,
    const float* __restrict__ x, ushort* __restrict__ xb,
    const float* __restrict__ Wl0, ushort* __restrict__ Wl0t,
    const float* __restrict__ Wr0, ushort* __restrict__ Wr0t,
    const float* __restrict__ Wl1, ushort* __restrict__ Wl1t,
    const float* __restrict__ Wr1, ushort* __restrict__ Wr1t,
    const float* __restrict__ Wl2, ushort* __restrict__ Wl2t,
    const float* __restrict__ Wr2, ushort* __restrict__ Wr2t)
{
    int i = blockIdx.x * blockDim.x + threadIdx.x;
    if (i < N_EDGES) { atomicAdd(&cnt[dst[i]], 1); return; }
    i -= N_EDGES;
    if (i < N4X) {
        float4 v = *(const float4*)&x[(size_t)i * 4];
        ushort4 o;
        o.x = f2bf(v.x); o.y = f2bf(v.y); o.z = f2bf(v.z); o.w = f2bf(v.w);
        *(ushort4*)&xb[(size_t)i * 4] = o;
        return;
    }
    i -= N4X;
    // slot-order transpose: q = i>>11, col = (i>>3)&255, e = i&7, k = q*8+e
#define WT2(Wsrc, Wdst, LIM) \
    if (i < (LIM)) { \
        int q = i >> 11, col = (i >> 3) & 255, e = i & 7; \
        Wdst[i] = f2bf(Wsrc[(q * 8 + e) * 256 + col]); \
        return; \
    } \
    i -= (LIM);
    WT2(Wl0, Wl0t, 32768)
    WT2(Wr0, Wr0t, 32768)
    WT2(Wl1, Wl1t, 65536)
    WT2(Wr1, Wr1t, 65536)
    WT2(Wl2, Wl2t, 65536)
    WT2(Wr2, Wr2t, 65536)
#undef WT2
}

// ---------------- CSR scan ----------------

__global__ __launch_bounds__(SCAN_T) void scan_partial(
    const int* __restrict__ cnt, int* __restrict__ bsum, int n)
{
    int chunk = (n + SCAN_BLOCKS - 1) / SCAN_BLOCKS;
    int beg = blockIdx.x * chunk;
    int end = beg + chunk; if (end > n) end = n;
    int t = threadIdx.x;
    int s = 0;
    for (int i = beg + t; i < end; i += SCAN_T) s += cnt[i];
    __shared__ int sh[SCAN_T];
    sh[t] = s;
    __syncthreads();
    for (int off = SCAN_T / 2; off > 0; off >>= 1) {
        if (t < off) sh[t] += sh[t + off];
        __syncthreads();
    }
    if (t == 0) bsum[blockIdx.x] = sh[0];
}

__global__ __launch_bounds__(SCAN_T) void scan_block_sums(int* __restrict__ bsum) {
    int t = threadIdx.x;
    __shared__ int sh[SCAN_T];
    int v = bsum[t];
    sh[t] = v;
    __syncthreads();
    for (int off = 1; off < SCAN_T; off <<= 1) {
        int u = (t >= off) ? sh[t - off] : 0;
        __syncthreads();
        sh[t] += u;
        __syncthreads();
    }
    bsum[t] = sh[t] - v;  // exclusive
}

__global__ __launch_bounds__(SCAN_T) void scan_fill(
    int* __restrict__ cnt, const int* __restrict__ bsum,
    int* __restrict__ row_ptr, int n)
{
    int chunk = (n + SCAN_BLOCKS - 1) / SCAN_BLOCKS;
    int beg = blockIdx.x * chunk;
    int end = beg + chunk; if (end > n) end = n;
    int t = threadIdx.x;
    int per = (chunk + SCAN_T - 1) / SCAN_T;
    int tb = beg + t * per;
    int te = tb + per; if (te > end) te = end;
    int s = 0;
    for (int i = tb; i < te; ++i) s += cnt[i];
    __shared__ int sh[SCAN_T];
    sh[t] = s;
    __syncthreads();
    for (int off = 1; off < SCAN_T; off <<= 1) {
        int u = (t >= off) ? sh[t - off] : 0;
        __syncthreads();
        sh[t] += u;
        __syncthreads();
    }
    int running = bsum[blockIdx.x] + sh[t] - s;
    for (int i = tb; i < te; ++i) {
        int c = cnt[i];
        row_ptr[i] = running;
        cnt[i] = running;  // becomes fill cursor
        running += c;
    }
    if (blockIdx.x == 0 && t == 0) row_ptr[n] = N_EDGES;
}

// 4 dst-range passes: per-pass dirty col_idx region (~1.6MB) stays L2-resident.
__global__ void fill_csr(const int* __restrict__ src, const int* __restrict__ dst,
                         int* __restrict__ cursor, int* __restrict__ col_idx) {
    int i = blockIdx.x * blockDim.x + threadIdx.x;
    if (i >= N_EDGES) return;
    int lo = (int)blockIdx.y * (N_NODES / FILL_PASSES);
    int hi = lo + (N_NODES / FILL_PASSES);
    int d = dst[i];
    if (d >= lo && d < hi) {
        int p = atomicAdd(&cursor[d], 1);
        col_idx[p] = src[i];
    }
}

// ---------------- mean aggregation (round-4 form, measured floor) ---------
__global__ __launch_bounds__(64) void aggregate_bf16(
    const ushort* __restrict__ xb, const int* __restrict__ row_ptr,
    const int* __restrict__ col_idx, ushort* __restrict__ outb, int F)
{
    int node = blockIdx.x;
    int t = threadIdx.x;
    int b = row_ptr[node], e = row_ptr[node + 1];
    float d = (float)(e - b); if (d < 1.f) d = 1.f;
    float inv = 1.f / d;

    if (F == 256) {
        int c = t * 4;
        float a0 = 0.f, a1 = 0.f, a2 = 0.f, a3 = 0.f;
        float b0 = 0.f, b1 = 0.f, b2 = 0.f, b3 = 0.f;
        int i = b;
        for (; i + 1 < e; i += 2) {
            int s0 = col_idx[i];
            int s1 = col_idx[i + 1];
            uint2 v0 = *(const uint2*)&xb[(size_t)s0 * 256 + c];
            uint2 v1 = *(const uint2*)&xb[(size_t)s1 * 256 + c];
            a0 += bf2f((ushort)(v0.x & 0xffff)); a1 += bf2f((ushort)(v0.x >> 16));
            a2 += bf2f((ushort)(v0.y & 0xffff)); a3 += bf2f((ushort)(v0.y >> 16));
            b0 += bf2f((ushort)(v1.x & 0xffff)); b1 += bf2f((ushort)(v1.x >> 16));
            b2 += bf2f((ushort)(v1.y & 0xffff)); b3 += bf2f((ushort)(v1.y >> 16));
        }
        if (i < e) {
            int s0 = col_idx[i];
            uint2 v0 = *(const uint2*)&xb[(size_t)s0 * 256 + c];
            a0 += bf2f((ushort)(v0.x & 0xffff)); a1 += bf2f((ushort)(v0.x >> 16));
            a2 += bf2f((ushort)(v0.y & 0xffff)); a3 += bf2f((ushort)(v0.y >> 16));
        }
        ushort4 o;
        o.x = f2bf((a0 + b0) * inv); o.y = f2bf((a1 + b1) * inv);
        o.z = f2bf((a2 + b2) * inv); o.w = f2bf((a3 + b3) * inv);
        *(ushort4*)&outb[(size_t)node * 256 + c] = o;
    } else {
        int c = t * 2;
        float a0 = 0.f, a1 = 0.f, b0 = 0.f, b1 = 0.f;
        int i = b;
        for (; i + 1 < e; i += 2) {
            int s0 = col_idx[i];
            int s1 = col_idx[i + 1];
            uint v0 = *(const uint*)&xb[(size_t)s0 * 128 + c];
            uint v1 = *(const uint*)&xb[(size_t)s1 * 128 + c];
            a0 += bf2f((ushort)(v0 & 0xffff)); a1 += bf2f((ushort)(v0 >> 16));
            b0 += bf2f((ushort)(v1 & 0xffff)); b1 += bf2f((ushort)(v1 >> 16));
        }
        if (i < e) {
            int s0 = col_idx[i];
            uint v0 = *(const uint*)&xb[(size_t)s0 * 128 + c];
            a0 += bf2f((ushort)(v0 & 0xffff)); a1 += bf2f((ushort)(v0 >> 16));
        }
        ushort2 o;
        o.x = f2bf((a0 + b0) * inv); o.y = f2bf((a1 + b1) * inv);
        *(ushort2*)&outb[(size_t)node * 128 + c] = o;
    }
}

// ---------------- K-chunked dual MFMA GEMM ----------------
// C[M,256] = relu?( A1[M,K]@W1 + A2[M,K]@W2 + bias ).
// 256 thr (4 waves), tile 128 rows x 256 cols. A read ONCE (full-col tile).
// W streamed through 2x32KB LDS chunks of 64 k each; stage of chunk c+1
// overlaps compute of chunk c. Wt2 is pre-laid-out in LDS slot order so
// staging reads are 16B/lane coalesced. 64KB LDS -> 2 blocks/CU.
__global__ __launch_bounds__(256, 2) void gemm_kc(
    const ushort* __restrict__ A1, const ushort* __restrict__ W1t,
    const ushort* __restrict__ A2, const ushort* __restrict__ W2t,
    const float* __restrict__ bias, ushort* __restrict__ out_bf,
    float* __restrict__ out_f32, int M, int K, int relu)
{
    __shared__ __align__(16) ushort Wl[2][2048 * 8];  // 2 x 32KB
    int tid = threadIdx.x;
    int w = tid >> 6, lane = tid & 63;
    int m_ = lane & 15, koq = lane >> 4;
    int row0 = blockIdx.x * 128;
    int nc = K >> 6;  // 64-k chunks per mm phase

    floatx4 acc[2][16];
#pragma unroll
    for (int i = 0; i < 2; ++i)
#pragma unroll
        for (int f = 0; f < 16; ++f) acc[i][f] = (floatx4){0.f, 0.f, 0.f, 0.f};

    int ra = row0 + w * 32 + m_;      if (ra > M - 1) ra = M - 1;
    int rb = row0 + w * 32 + 16 + m_; if (rb > M - 1) rb = M - 1;

#define STAGE(c, buf) \
    { \
        const ushort* _s = &Wt[(size_t)(c) * 16384 + tid * 8]; \
        _Pragma("unroll") \
        for (int j = 0; j < 8; ++j) { \
            __builtin_amdgcn_global_load_lds( \
                (const AS1 uint*)&_s[(size_t)j * 2048], \
                (AS3 uint*)&Wl[buf][(j * 256 + w * 64) * 8], 16, 0, 0); \
        } \
    }

    for (int mm = 0; mm < 2; ++mm) {
        const ushort* __restrict__ A  = mm ? A2 : A1;
        const ushort* __restrict__ Wt = mm ? W2t : W1t;
        const ushort* __restrict__ Aa = &A[(size_t)ra * K + koq * 8];
        const ushort* __restrict__ Ab = &A[(size_t)rb * K + koq * 8];

        STAGE(0, 0)
        short8 a0 = *(const short8*)&Aa[0];
        short8 a1 = *(const short8*)&Ab[0];
        short8 a2 = *(const short8*)&Aa[32];
        short8 a3 = *(const short8*)&Ab[32];
        __syncthreads();  // chunk 0 DMA drained

        for (int c = 0; c < nc; ++c) {
            short8 n0, n1, n2, n3;
            if (c + 1 < nc) {
                STAGE(c + 1, (c + 1) & 1)
                n0 = *(const short8*)&Aa[(c + 1) * 64];
                n1 = *(const short8*)&Ab[(c + 1) * 64];
                n2 = *(const short8*)&Aa[(c + 1) * 64 + 32];
                n3 = *(const short8*)&Ab[(c + 1) * 64 + 32];
            }
            int buf = c & 1;
#pragma unroll
            for (int kk = 0; kk < 2; ++kk) {
                const ushort* bb = &Wl[buf][((kk * 4 + koq) * 256 + m_) * 8];
                short8 aA = kk ? a2 : a0;
                short8 aB = kk ? a3 : a1;
#pragma unroll
                for (int fc = 0; fc < 16; ++fc) {
                    short8 b = *(const short8*)&bb[fc * 128];
                    acc[0][fc] = __builtin_amdgcn_mfma_f32_16x16x32_bf16(aA, b, acc[0][fc], 0, 0, 0);
                    acc[1][fc] = __builtin_amdgcn_mfma_f32_16x16x32_bf16(aB, b, acc[1][fc], 0, 0, 0);
                }
            }
            __syncthreads();  // drain chunk c+1 DMA; protect buf reuse
            a0 = n0; a1 = n1; a2 = n2; a3 = n3;
        }
    }
#undef STAGE

    // epilogue: frag C layout col = m_, row = koq*4 + r
#pragma unroll
    for (int m2 = 0; m2 < 2; ++m2) {
#pragma unroll
        for (int fc = 0; fc < 16; ++fc) {
            int col = fc * 16 + m_;
            float bv = bias[col];
#pragma unroll
            for (int r = 0; r < 4; ++r) {
                int row = row0 + w * 32 + m2 * 16 + koq * 4 + r;
                if (row >= M) continue;
                float v = acc[m2][fc][r] + bv;
                if (relu) v = fmaxf(v, 0.f);
                if (out_f32) out_f32[(size_t)row * 256 + col] = v;
                else         out_bf [(size_t)row * 256 + col] = f2bf(v);
            }
        }
    }
}

// ---------------- launch ----------------

extern "C" void kernel_launch(void* const* d_in, const int* in_sizes, int n_in,
                              void* d_out, int out_size, void* d_ws, size_t ws_size,
                              hipStream_t stream) {
    const float* x    = (const float*)d_in[0];
    const float* W_l0 = (const float*)d_in[1];
    const float* b_l0 = (const float*)d_in[2];
    const float* W_r0 = (const float*)d_in[3];
    const float* W_l1 = (const float*)d_in[4];
    const float* b_l1 = (const float*)d_in[5];
    const float* W_r1 = (const float*)d_in[6];
    const float* W_l2 = (const float*)d_in[7];
    const float* b_l2 = (const float*)d_in[8];
    const float* W_r2 = (const float*)d_in[9];
    const int* esrc   = (const int*)d_in[10];
    const int* edst   = (const int*)d_in[11];
    float* out = (float*)d_out;

    size_t off = 0;
    char* ws = (char*)d_ws;
    auto take = [&](size_t bytes) -> void* {
        void* p = ws + off;
        off += (bytes + 255) & ~(size_t)255;
        return p;
    };
    int*    cnt     = (int*)take((size_t)N_NODES * 4);
    int*    row_ptr = (int*)take((size_t)(N_NODES + 1) * 4);
    int*    col_idx = (int*)take((size_t)N_EDGES * 4);
    int*    bsum    = (int*)take((size_t)SCAN_BLOCKS * 4);
    ushort* xb      = (ushort*)take((size_t)N_NODES * 128 * 2);
    ushort* Wl0t    = (ushort*)take((size_t)256 * 128 * 2);
    ushort* Wr0t    = (ushort*)take((size_t)256 * 128 * 2);
    ushort* Wl1t    = (ushort*)take((size_t)256 * 256 * 2);
    ushort* Wr1t    = (ushort*)take((size_t)256 * 256 * 2);
    ushort* Wl2t    = (ushort*)take((size_t)256 * 256 * 2);
    ushort* Wr2t    = (ushort*)take((size_t)256 * 256 * 2);
    ushort* aggrb   = (ushort*)take((size_t)N_NODES * 256 * 2);
    ushort* ha      = (ushort*)take((size_t)N_NODES * 256 * 2);
    ushort* hb      = (ushort*)take((size_t)N_NODES * 256 * 2);
    (void)ws_size; (void)in_sizes; (void)n_in; (void)out_size;

    // prep: zero cnt, then fused count+convert+transposes
    hipMemsetAsync(cnt, 0, (size_t)N_NODES * 4, stream);
    int total_prep = N_EDGES + N4X + 2 * 32768 + 4 * 65536;
    prep_all<<<(total_prep + 255) / 256, 256, 0, stream>>>(
        edst, cnt, x, xb,
        W_l0, Wl0t, W_r0, Wr0t, W_l1, Wl1t, W_r1, Wr1t, W_l2, Wl2t, W_r2, Wr2t);

    // CSR scan + fill
    scan_partial<<<SCAN_BLOCKS, SCAN_T, 0, stream>>>(cnt, bsum, N_NODES);
    scan_block_sums<<<1, SCAN_T, 0, stream>>>(bsum);
    scan_fill<<<SCAN_BLOCKS, SCAN_T, 0, stream>>>(cnt, bsum, row_ptr, N_NODES);
    int eb = (N_EDGES + 255) / 256;
    fill_csr<<<dim3(eb, FILL_PASSES), 256, 0, stream>>>(esrc, edst, cnt, col_idx);

    dim3 ggrid((N_NODES + 127) / 128, 1);

    // layer 0: 128 -> 256, relu
    aggregate_bf16<<<N_NODES, 64, 0, stream>>>(xb, row_ptr, col_idx, aggrb, 128);
    gemm_kc<<<ggrid, 256, 0, stream>>>(aggrb, Wl0t, xb, Wr0t, b_l0,
                                       ha, nullptr, N_NODES, 128, 1);
    // layer 1: 256 -> 256, relu
    aggregate_bf16<<<N_NODES, 64, 0, stream>>>(ha, row_ptr, col_idx, aggrb, 256);
    gemm_kc<<<ggrid, 256, 0, stream>>>(aggrb, Wl1t, ha, Wr1t, b_l1,
                                       hb, nullptr, N_NODES, 256, 1);
    // layer 2: 256 -> 256, no relu, fp32 out
    aggregate_bf16<<<N_NODES, 64, 0, stream>>>(hb, row_ptr, col_idx, aggrb, 256);
    gemm_kc<<<ggrid, 256, 0, stream>>>(aggrb, Wl2t, hb, Wr2t, b_l2,
                                       nullptr, out, N_NODES, 256, 0);
}